// Round 1
// baseline (1114.327 us; speedup 1.0000x reference)
//
#include <hip/hip_runtime.h>

// GCN layer: h = x@W + b; pre[i] = sum_{e: row_e==i} w_e * h[col_e]; out = elu(pre)
// d_out = [pre (N*H fp32) | elu(pre) (N*H fp32)]

#define D 96
#define CG (D / 4)          // 24 float4 chunks per row
#define ROWS_PER_BLOCK 32

// ---------------- Kernel 1: h = x @ W + b (fp32, LDS-tiled) ----------------
__global__ __launch_bounds__(256) void gemm_bias_kernel(
    const float* __restrict__ x, const float* __restrict__ W,
    const float* __restrict__ b, float* __restrict__ h, int n_nodes) {
  __shared__ float sW[D * D];               // 36 KB
  __shared__ float sX[ROWS_PER_BLOCK * D];  // 12 KB
  const int tid = threadIdx.x;

  // Stage W (9216 floats = 2304 float4)
  const float4* W4 = (const float4*)W;
  float4* sW4 = (float4*)sW;
  for (int i = tid; i < D * CG; i += 256) sW4[i] = W4[i];

  // Stage x tile (rows row0..row0+31), zero-pad past n_nodes
  const int row0 = blockIdx.x * ROWS_PER_BLOCK;
  float4* sX4 = (float4*)sX;
  for (int i = tid; i < ROWS_PER_BLOCK * CG; i += 256) {
    const int r = row0 + i / CG;
    float4 v = make_float4(0.f, 0.f, 0.f, 0.f);
    if (r < n_nodes) v = ((const float4*)x)[(long long)r * CG + (i % CG)];
    sX4[i] = v;
  }
  __syncthreads();

  // 32 rows x 24 col-groups = 768 tasks, 3 per thread
  for (int t = tid; t < ROWS_PER_BLOCK * CG; t += 256) {
    const int r = t / CG, cg = t % CG;
    float4 a = ((const float4*)b)[cg];
    const float* xr = sX + r * D;
#pragma unroll
    for (int k = 0; k < D; ++k) {
      const float xv = xr[k];
      const float4 w = ((const float4*)(sW + k * D))[cg];
      a.x = fmaf(xv, w.x, a.x);
      a.y = fmaf(xv, w.y, a.y);
      a.z = fmaf(xv, w.z, a.z);
      a.w = fmaf(xv, w.w, a.w);
    }
    const int row = row0 + r;
    if (row < n_nodes) ((float4*)h)[(long long)row * CG + cg] = a;
  }
}

// ---------------- Kernel 2: scatter-add messages ----------------
// 24 threads per edge; thread handles one float4 of the feature row.
__global__ __launch_bounds__(256) void scatter_kernel(
    const int* __restrict__ rows, const int* __restrict__ cols,
    const float* __restrict__ ew, const float* __restrict__ h,
    float* __restrict__ pre, int n_edges) {
  const int gid = blockIdx.x * 256 + threadIdx.x;
  const int e = gid / CG;
  const int cg = gid - e * CG;
  if (e >= n_edges) return;
  const int r = rows[e];
  const int c = cols[e];
  const float we = ew[e];
  const float4 hv = ((const float4*)h)[(long long)c * CG + cg];
  float* dst = pre + (long long)r * D + cg * 4;
  atomicAdd(dst + 0, we * hv.x);
  atomicAdd(dst + 1, we * hv.y);
  atomicAdd(dst + 2, we * hv.z);
  atomicAdd(dst + 3, we * hv.w);
}

// ---------------- Kernel 3: elementwise ELU ----------------
__global__ __launch_bounds__(256) void elu_kernel(
    const float* __restrict__ pre, float* __restrict__ out, int n4) {
  const int i = blockIdx.x * 256 + threadIdx.x;
  if (i >= n4) return;
  const float4 v = ((const float4*)pre)[i];
  float4 o;
  o.x = v.x > 0.f ? v.x : (__expf(v.x) - 1.f);
  o.y = v.y > 0.f ? v.y : (__expf(v.y) - 1.f);
  o.z = v.z > 0.f ? v.z : (__expf(v.z) - 1.f);
  o.w = v.w > 0.f ? v.w : (__expf(v.w) - 1.f);
  ((float4*)out)[i] = o;
}

extern "C" void kernel_launch(void* const* d_in, const int* in_sizes, int n_in,
                              void* d_out, int out_size, void* d_ws, size_t ws_size,
                              hipStream_t stream) {
  const float* x  = (const float*)d_in[0];
  const float* W  = (const float*)d_in[1];
  const float* b  = (const float*)d_in[2];
  const int*   ei = (const int*)d_in[3];
  const float* ew = (const float*)d_in[4];

  const int n_nodes = in_sizes[0] / D;
  const int n_edges = in_sizes[4];
  const int* rows = ei;
  const int* cols = ei + n_edges;

  float* pre  = (float*)d_out;                       // first N*H floats
  float* outp = pre + (size_t)n_nodes * D;           // second N*H floats
  float* h    = (float*)d_ws;                        // scratch: N*H fp32 = 19.2 MB

  // zero the accumulation target (harness poisons d_out with 0xAA)
  hipMemsetAsync(pre, 0, (size_t)n_nodes * D * sizeof(float), stream);

  const int gemm_blocks = (n_nodes + ROWS_PER_BLOCK - 1) / ROWS_PER_BLOCK;
  gemm_bias_kernel<<<gemm_blocks, 256, 0, stream>>>(x, W, b, h, n_nodes);

  const long long total = (long long)n_edges * CG;
  const int scat_blocks = (int)((total + 255) / 256);
  scatter_kernel<<<scat_blocks, 256, 0, stream>>>(rows, cols, ew, h, pre, n_edges);

  const int n4 = n_nodes * CG;
  elu_kernel<<<(n4 + 255) / 256, 256, 0, stream>>>(pre, outp, n4);
}

// Round 2
// 337.686 us; speedup vs baseline: 3.2999x; 3.2999x over previous
//
#include <hip/hip_runtime.h>

// GCN layer: h = x@W + b; pre[i] = sum_{e: row_e==i} w_e * h[col_e]; out = elu(pre)
// d_out = [pre (N*H fp32) | elu(pre) (N*H fp32)]
//
// R2: replace fp32 atomic scatter (1.2 GB HBM write traffic) with on-the-fly
// counting sort by destination row + register-accumulating gather (no fp32 atomics).

#define D 96
#define CG (D / 4)
#define ROWS_PER_BLOCK 32
#define SCAN_THREADS 1024
#define GROUPS_PER_BLOCK 8   // 32-thread groups per 256-block in gather

// ---------------- Kernel 1: h = x @ W + b (fp32, LDS-tiled) ----------------
__global__ __launch_bounds__(256) void gemm_bias_kernel(
    const float* __restrict__ x, const float* __restrict__ W,
    const float* __restrict__ b, float* __restrict__ h, int n_nodes) {
  __shared__ float sW[D * D];
  __shared__ float sX[ROWS_PER_BLOCK * D];
  const int tid = threadIdx.x;

  const float4* W4 = (const float4*)W;
  float4* sW4 = (float4*)sW;
  for (int i = tid; i < D * CG; i += 256) sW4[i] = W4[i];

  const int row0 = blockIdx.x * ROWS_PER_BLOCK;
  float4* sX4 = (float4*)sX;
  for (int i = tid; i < ROWS_PER_BLOCK * CG; i += 256) {
    const int r = row0 + i / CG;
    float4 v = make_float4(0.f, 0.f, 0.f, 0.f);
    if (r < n_nodes) v = ((const float4*)x)[(long long)r * CG + (i % CG)];
    sX4[i] = v;
  }
  __syncthreads();

  for (int t = tid; t < ROWS_PER_BLOCK * CG; t += 256) {
    const int r = t / CG, cg = t % CG;
    float4 a = ((const float4*)b)[cg];
    const float* xr = sX + r * D;
#pragma unroll
    for (int k = 0; k < D; ++k) {
      const float xv = xr[k];
      const float4 w = ((const float4*)(sW + k * D))[cg];
      a.x = fmaf(xv, w.x, a.x);
      a.y = fmaf(xv, w.y, a.y);
      a.z = fmaf(xv, w.z, a.z);
      a.w = fmaf(xv, w.w, a.w);
    }
    const int row = row0 + r;
    if (row < n_nodes) ((float4*)h)[(long long)row * CG + cg] = a;
  }
}

// ---------------- Kernel 2a: histogram of destination rows ----------------
__global__ __launch_bounds__(256) void hist_kernel(
    const int* __restrict__ rows, int* __restrict__ counts, int n_edges) {
  const int e = blockIdx.x * 256 + threadIdx.x;
  if (e < n_edges) atomicAdd(&counts[rows[e]], 1);
}

// ---------------- Kernel 2b: exclusive scan (single block) ----------------
__global__ __launch_bounds__(SCAN_THREADS) void scan_kernel(
    const int* __restrict__ counts, int* __restrict__ seg_start,
    int* __restrict__ cursor, int n) {
  __shared__ int buf[SCAN_THREADS];
  __shared__ int carry;
  const int tid = threadIdx.x;
  if (tid == 0) carry = 0;
  __syncthreads();
  for (int base = 0; base < n; base += SCAN_THREADS) {
    const int i = base + tid;
    const int v = (i < n) ? counts[i] : 0;
    buf[tid] = v;
    __syncthreads();
#pragma unroll
    for (int off = 1; off < SCAN_THREADS; off <<= 1) {
      int t = (tid >= off) ? buf[tid - off] : 0;
      __syncthreads();
      buf[tid] += t;
      __syncthreads();
    }
    const int excl = buf[tid] - v + carry;
    if (i < n) { seg_start[i] = excl; cursor[i] = excl; }
    __syncthreads();
    if (tid == 0) carry += buf[SCAN_THREADS - 1];
    __syncthreads();
  }
}

// ---------------- Kernel 2c: permute (col, w) into row-sorted order ----------
__global__ __launch_bounds__(256) void permute_kernel(
    const int* __restrict__ rows, const int* __restrict__ cols,
    const float* __restrict__ ew, int* __restrict__ cursor,
    int* __restrict__ scol, float* __restrict__ sw, int n_edges) {
  const int e = blockIdx.x * 256 + threadIdx.x;
  if (e >= n_edges) return;
  const int pos = atomicAdd(&cursor[rows[e]], 1);
  scol[pos] = cols[e];
  sw[pos] = ew[e];
}

// ---------------- Kernel 3: per-row gather + accumulate + fused ELU ----------
__global__ __launch_bounds__(256) void gather_kernel(
    const int* __restrict__ seg_start, const int* __restrict__ counts,
    const int* __restrict__ scol, const float* __restrict__ sw,
    const float* __restrict__ h, float* __restrict__ pre,
    float* __restrict__ out, int n_nodes) {
  const int g = threadIdx.x >> 5;
  const int lane = threadIdx.x & 31;
  const int row = blockIdx.x * GROUPS_PER_BLOCK + g;
  if (row >= n_nodes) return;
  const int s = seg_start[row];
  const int e = s + counts[row];
  float a0 = 0.f, a1 = 0.f, a2 = 0.f;
  int k = s;
  // 2x unroll for ILP on the L2-latency-bound h reads
  for (; k + 1 < e; k += 2) {
    const int c0 = scol[k], c1 = scol[k + 1];
    const float w0 = sw[k], w1 = sw[k + 1];
    const float* h0 = h + (size_t)c0 * D;
    const float* h1 = h + (size_t)c1 * D;
    const float p00 = h0[lane], p01 = h0[lane + 32], p02 = h0[lane + 64];
    const float p10 = h1[lane], p11 = h1[lane + 32], p12 = h1[lane + 64];
    a0 = fmaf(w0, p00, a0); a1 = fmaf(w0, p01, a1); a2 = fmaf(w0, p02, a2);
    a0 = fmaf(w1, p10, a0); a1 = fmaf(w1, p11, a1); a2 = fmaf(w1, p12, a2);
  }
  if (k < e) {
    const int c = scol[k];
    const float w = sw[k];
    const float* hr = h + (size_t)c * D;
    a0 = fmaf(w, hr[lane], a0);
    a1 = fmaf(w, hr[lane + 32], a1);
    a2 = fmaf(w, hr[lane + 64], a2);
  }
  float* pr = pre + (size_t)row * D;
  float* orow = out + (size_t)row * D;
  pr[lane] = a0; pr[lane + 32] = a1; pr[lane + 64] = a2;
  orow[lane]      = a0 > 0.f ? a0 : (__expf(a0) - 1.f);
  orow[lane + 32] = a1 > 0.f ? a1 : (__expf(a1) - 1.f);
  orow[lane + 64] = a2 > 0.f ? a2 : (__expf(a2) - 1.f);
}

extern "C" void kernel_launch(void* const* d_in, const int* in_sizes, int n_in,
                              void* d_out, int out_size, void* d_ws, size_t ws_size,
                              hipStream_t stream) {
  const float* x  = (const float*)d_in[0];
  const float* W  = (const float*)d_in[1];
  const float* b  = (const float*)d_in[2];
  const int*   ei = (const int*)d_in[3];
  const float* ew = (const float*)d_in[4];

  const int n_nodes = in_sizes[0] / D;
  const int n_edges = in_sizes[4];
  const int* rows = ei;
  const int* cols = ei + n_edges;

  float* pre  = (float*)d_out;
  float* outp = pre + (size_t)n_nodes * D;

  // workspace layout
  char* ws = (char*)d_ws;
  float* h        = (float*)ws;                       ws += (size_t)n_nodes * D * sizeof(float);
  int*   counts   = (int*)ws;                         ws += (size_t)n_nodes * sizeof(int);
  int*   seg      = (int*)ws;                         ws += (size_t)n_nodes * sizeof(int);
  int*   cursor   = (int*)ws;                         ws += (size_t)n_nodes * sizeof(int);
  int*   scol     = (int*)ws;                         ws += (size_t)n_edges * sizeof(int);
  float* sw       = (float*)ws;

  hipMemsetAsync(counts, 0, (size_t)n_nodes * sizeof(int), stream);

  const int gemm_blocks = (n_nodes + ROWS_PER_BLOCK - 1) / ROWS_PER_BLOCK;
  gemm_bias_kernel<<<gemm_blocks, 256, 0, stream>>>(x, W, b, h, n_nodes);

  const int eb = (n_edges + 255) / 256;
  hist_kernel<<<eb, 256, 0, stream>>>(rows, counts, n_edges);
  scan_kernel<<<1, SCAN_THREADS, 0, stream>>>(counts, seg, cursor, n_nodes);
  permute_kernel<<<eb, 256, 0, stream>>>(rows, cols, ew, cursor, scol, sw, n_edges);

  const int gb = (n_nodes + GROUPS_PER_BLOCK - 1) / GROUPS_PER_BLOCK;
  gather_kernel<<<gb, 256, 0, stream>>>(seg, counts, scol, sw, h, pre, outp, n_nodes);
}

// Round 3
// 251.528 us; speedup vs baseline: 4.4302x; 1.3425x over previous
//
#include <hip/hip_runtime.h>

// GCN layer: h = x@W + b; pre[i] = sum_{e: row_e==i} w_e * h[col_e]; out = elu(pre)
// d_out = [pre (N*H fp32) | elu(pre) (N*H fp32)]
//
// R3: replace 93.7us single-block scan with 3-kernel hierarchical scan (~10us).

#define D 96
#define CG (D / 4)
#define ROWS_PER_BLOCK 32
#define GROUPS_PER_BLOCK 8
#define CHUNK 2048  // elements per scan block (256 threads x 8)

// ---------------- Kernel 1: h = x @ W + b (fp32, LDS-tiled) ----------------
__global__ __launch_bounds__(256) void gemm_bias_kernel(
    const float* __restrict__ x, const float* __restrict__ W,
    const float* __restrict__ b, float* __restrict__ h, int n_nodes) {
  __shared__ float sW[D * D];
  __shared__ float sX[ROWS_PER_BLOCK * D];
  const int tid = threadIdx.x;

  const float4* W4 = (const float4*)W;
  float4* sW4 = (float4*)sW;
  for (int i = tid; i < D * CG; i += 256) sW4[i] = W4[i];

  const int row0 = blockIdx.x * ROWS_PER_BLOCK;
  float4* sX4 = (float4*)sX;
  for (int i = tid; i < ROWS_PER_BLOCK * CG; i += 256) {
    const int r = row0 + i / CG;
    float4 v = make_float4(0.f, 0.f, 0.f, 0.f);
    if (r < n_nodes) v = ((const float4*)x)[(long long)r * CG + (i % CG)];
    sX4[i] = v;
  }
  __syncthreads();

  for (int t = tid; t < ROWS_PER_BLOCK * CG; t += 256) {
    const int r = t / CG, cg = t % CG;
    float4 a = ((const float4*)b)[cg];
    const float* xr = sX + r * D;
#pragma unroll
    for (int k = 0; k < D; ++k) {
      const float xv = xr[k];
      const float4 w = ((const float4*)(sW + k * D))[cg];
      a.x = fmaf(xv, w.x, a.x);
      a.y = fmaf(xv, w.y, a.y);
      a.z = fmaf(xv, w.z, a.z);
      a.w = fmaf(xv, w.w, a.w);
    }
    const int row = row0 + r;
    if (row < n_nodes) ((float4*)h)[(long long)row * CG + cg] = a;
  }
}

// ---------------- Kernel 2a: histogram of destination rows ----------------
__global__ __launch_bounds__(256) void hist_kernel(
    const int* __restrict__ rows, int* __restrict__ counts, int n_edges) {
  const int e = blockIdx.x * 256 + threadIdx.x;
  if (e < n_edges) atomicAdd(&counts[rows[e]], 1);
}

// ---------------- Kernel 2b-1: per-chunk sums ----------------
__global__ __launch_bounds__(256) void block_sum_kernel(
    const int* __restrict__ counts, int* __restrict__ bsum, int n) {
  __shared__ int red[256];
  const int tid = threadIdx.x;
  const int base = blockIdx.x * CHUNK;
  int s = 0;
#pragma unroll
  for (int j = 0; j < 8; ++j) {
    const int i = base + j * 256 + tid;
    if (i < n) s += counts[i];
  }
  red[tid] = s;
  __syncthreads();
  for (int off = 128; off > 0; off >>= 1) {
    if (tid < off) red[tid] += red[tid + off];
    __syncthreads();
  }
  if (tid == 0) bsum[blockIdx.x] = red[0];
}

// ---------------- Kernel 2b-2: exclusive scan of chunk sums (nb <= 256) ------
__global__ __launch_bounds__(256) void scan_bsum_kernel(int* __restrict__ bsum, int nb) {
  __shared__ int buf[256];
  const int tid = threadIdx.x;
  const int v = (tid < nb) ? bsum[tid] : 0;
  buf[tid] = v;
  __syncthreads();
  for (int off = 1; off < 256; off <<= 1) {
    const int t = (tid >= off) ? buf[tid - off] : 0;
    __syncthreads();
    buf[tid] += t;
    __syncthreads();
  }
  if (tid < nb) bsum[tid] = buf[tid] - v;  // exclusive
}

// ---------------- Kernel 2b-3: per-chunk exclusive scan + offset ----------
__global__ __launch_bounds__(256) void scan_chunk_kernel(
    const int* __restrict__ counts, const int* __restrict__ bsum,
    int* __restrict__ seg, int* __restrict__ cursor, int n) {
  __shared__ int tsum[256];
  const int tid = threadIdx.x;
  const int base = blockIdx.x * CHUNK + tid * 8;
  int v[8];
  int s = 0;
#pragma unroll
  for (int j = 0; j < 8; ++j) {
    const int i = base + j;
    v[j] = (i < n) ? counts[i] : 0;
    s += v[j];
  }
  tsum[tid] = s;
  __syncthreads();
  const int mysum = s;
  for (int off = 1; off < 256; off <<= 1) {
    const int t = (tid >= off) ? tsum[tid - off] : 0;
    __syncthreads();
    tsum[tid] += t;
    __syncthreads();
  }
  int excl = tsum[tid] - mysum + bsum[blockIdx.x];
#pragma unroll
  for (int j = 0; j < 8; ++j) {
    const int i = base + j;
    if (i < n) { seg[i] = excl; cursor[i] = excl; }
    excl += v[j];
  }
}

// ---------------- Kernel 2c: permute (col, w) into row-sorted order ----------
__global__ __launch_bounds__(256) void permute_kernel(
    const int* __restrict__ rows, const int* __restrict__ cols,
    const float* __restrict__ ew, int* __restrict__ cursor,
    int* __restrict__ scol, float* __restrict__ sw, int n_edges) {
  const int e = blockIdx.x * 256 + threadIdx.x;
  if (e >= n_edges) return;
  const int pos = atomicAdd(&cursor[rows[e]], 1);
  scol[pos] = cols[e];
  sw[pos] = ew[e];
}

// ---------------- Kernel 3: per-row gather + accumulate + fused ELU ----------
__global__ __launch_bounds__(256) void gather_kernel(
    const int* __restrict__ seg_start, const int* __restrict__ counts,
    const int* __restrict__ scol, const float* __restrict__ sw,
    const float* __restrict__ h, float* __restrict__ pre,
    float* __restrict__ out, int n_nodes) {
  const int g = threadIdx.x >> 5;
  const int lane = threadIdx.x & 31;
  const int row = blockIdx.x * GROUPS_PER_BLOCK + g;
  if (row >= n_nodes) return;
  const int s = seg_start[row];
  const int e = s + counts[row];
  float a0 = 0.f, a1 = 0.f, a2 = 0.f;
  int k = s;
  for (; k + 1 < e; k += 2) {
    const int c0 = scol[k], c1 = scol[k + 1];
    const float w0 = sw[k], w1 = sw[k + 1];
    const float* h0 = h + (size_t)c0 * D;
    const float* h1 = h + (size_t)c1 * D;
    const float p00 = h0[lane], p01 = h0[lane + 32], p02 = h0[lane + 64];
    const float p10 = h1[lane], p11 = h1[lane + 32], p12 = h1[lane + 64];
    a0 = fmaf(w0, p00, a0); a1 = fmaf(w0, p01, a1); a2 = fmaf(w0, p02, a2);
    a0 = fmaf(w1, p10, a0); a1 = fmaf(w1, p11, a1); a2 = fmaf(w1, p12, a2);
  }
  if (k < e) {
    const int c = scol[k];
    const float w = sw[k];
    const float* hr = h + (size_t)c * D;
    a0 = fmaf(w, hr[lane], a0);
    a1 = fmaf(w, hr[lane + 32], a1);
    a2 = fmaf(w, hr[lane + 64], a2);
  }
  float* pr = pre + (size_t)row * D;
  float* orow = out + (size_t)row * D;
  pr[lane] = a0; pr[lane + 32] = a1; pr[lane + 64] = a2;
  orow[lane]      = a0 > 0.f ? a0 : (__expf(a0) - 1.f);
  orow[lane + 32] = a1 > 0.f ? a1 : (__expf(a1) - 1.f);
  orow[lane + 64] = a2 > 0.f ? a2 : (__expf(a2) - 1.f);
}

extern "C" void kernel_launch(void* const* d_in, const int* in_sizes, int n_in,
                              void* d_out, int out_size, void* d_ws, size_t ws_size,
                              hipStream_t stream) {
  const float* x  = (const float*)d_in[0];
  const float* W  = (const float*)d_in[1];
  const float* b  = (const float*)d_in[2];
  const int*   ei = (const int*)d_in[3];
  const float* ew = (const float*)d_in[4];

  const int n_nodes = in_sizes[0] / D;
  const int n_edges = in_sizes[4];
  const int* rows = ei;
  const int* cols = ei + n_edges;

  float* pre  = (float*)d_out;
  float* outp = pre + (size_t)n_nodes * D;

  // workspace layout
  char* ws = (char*)d_ws;
  float* h        = (float*)ws;  ws += (size_t)n_nodes * D * sizeof(float);
  int*   counts   = (int*)ws;    ws += (size_t)n_nodes * sizeof(int);
  int*   seg      = (int*)ws;    ws += (size_t)n_nodes * sizeof(int);
  int*   cursor   = (int*)ws;    ws += (size_t)n_nodes * sizeof(int);
  int*   bsum     = (int*)ws;    ws += 256 * sizeof(int);
  int*   scol     = (int*)ws;    ws += (size_t)n_edges * sizeof(int);
  float* sw       = (float*)ws;

  hipMemsetAsync(counts, 0, (size_t)n_nodes * sizeof(int), stream);

  const int gemm_blocks = (n_nodes + ROWS_PER_BLOCK - 1) / ROWS_PER_BLOCK;
  gemm_bias_kernel<<<gemm_blocks, 256, 0, stream>>>(x, W, b, h, n_nodes);

  const int eb = (n_edges + 255) / 256;
  hist_kernel<<<eb, 256, 0, stream>>>(rows, counts, n_edges);

  const int nb = (n_nodes + CHUNK - 1) / CHUNK;  // 25 for N=50000 (<=256 required)
  block_sum_kernel<<<nb, 256, 0, stream>>>(counts, bsum, n_nodes);
  scan_bsum_kernel<<<1, 256, 0, stream>>>(bsum, nb);
  scan_chunk_kernel<<<nb, 256, 0, stream>>>(counts, bsum, seg, cursor, n_nodes);

  permute_kernel<<<eb, 256, 0, stream>>>(rows, cols, ew, cursor, scol, sw, n_edges);

  const int gb = (n_nodes + GROUPS_PER_BLOCK - 1) / GROUPS_PER_BLOCK;
  gather_kernel<<<gb, 256, 0, stream>>>(seg, counts, scol, sw, h, pre, outp, n_nodes);
}